// Round 1
// baseline (16233.197 us; speedup 1.0000x reference)
//
#include <hip/hip_runtime.h>

// Problem constants
#define Bn   512
#define Tn   1024
#define Fn   64
#define Hn   512
#define NB1  128                 // LSTM1 blocks: 8 rt x 16 utp
#define NB2  16                  // LSTM2 blocks: 8 rt x 2 u2
#define NBLK (NB1 + NB2)
#define GMEM 18                  // barrier members per rt group: 16 + 2

typedef short bf16x8 __attribute__((ext_vector_type(8)));
typedef float f32x4  __attribute__((ext_vector_type(4)));

__device__ __forceinline__ short f2bf(float f) {
    union { float f; unsigned u; } v; v.f = f;
    unsigned r = (v.u + 0x7FFFu + ((v.u >> 16) & 1u)) >> 16;  // RNE
    return (short)(unsigned short)r;
}
__device__ __forceinline__ float sigm(float x) { return 1.f / (1.f + __expf(-x)); }
__device__ __forceinline__ float tanh_(float x) { return 2.f / (1.f + __expf(-2.f * x)) - 1.f; }

__device__ __forceinline__ bf16x8 cvt8(const float* p) {
    const float4 v0 = *(const float4*)p;
    const float4 v1 = *(const float4*)(p + 4);
    bf16x8 a;
    a[0] = f2bf(v0.x); a[1] = f2bf(v0.y); a[2] = f2bf(v0.z); a[3] = f2bf(v0.w);
    a[4] = f2bf(v1.x); a[5] = f2bf(v1.y); a[6] = f2bf(v1.z); a[7] = f2bf(v1.w);
    return a;
}

// -------- device-coherent (MALL-level) state exchange: relaxed agent atomics --------
// Bypass the (non-coherent) per-XCD L2 entirely: no acquire/invalidate needed, and
// the L2-cached weights/x stay resident across all 1024 steps.
__device__ __forceinline__ unsigned long long ld64(const short* p) {
    return __hip_atomic_load((const unsigned long long*)p, __ATOMIC_RELAXED, __HIP_MEMORY_SCOPE_AGENT);
}
__device__ __forceinline__ bf16x8 ld16B(const short* p) {
    union { unsigned long long u[2]; bf16x8 v; } x;
    x.u[0] = ld64(p);
    x.u[1] = ld64(p + 4);
    return x.v;
}
__device__ __forceinline__ void st2(short* p, short v) {
    __hip_atomic_store((unsigned short*)p, (unsigned short)v, __ATOMIC_RELAXED, __HIP_MEMORY_SCOPE_AGENT);
}

// Split barrier: arrive (release this block's drained stores, bump the count) and
// wait (spin on generation). Between arrive(t+1) and wait(t+1) a block may do any
// work that does not touch the exchanged state (we put the x-part GEMM there).
__device__ __forceinline__ void bar_arrive(unsigned* cnt, unsigned* gen, unsigned target) {
    __syncthreads();   // all waves' state stores drained (vmcnt(0) before s_barrier)
    if (threadIdx.x == 0) {
        unsigned a = __hip_atomic_fetch_add(cnt, 1u, __ATOMIC_RELEASE, __HIP_MEMORY_SCOPE_AGENT);
        if (a == GMEM - 1u) {
            __hip_atomic_store(cnt, 0u, __ATOMIC_RELAXED, __HIP_MEMORY_SCOPE_AGENT);
            __hip_atomic_store(gen, target, __ATOMIC_RELEASE, __HIP_MEMORY_SCOPE_AGENT);
        }
    }
}
__device__ __forceinline__ void bar_wait(unsigned* gen, unsigned target) {
    if (threadIdx.x == 0) {
        long spins = 0;
        while (__hip_atomic_load(gen, __ATOMIC_RELAXED, __HIP_MEMORY_SCOPE_AGENT) < target) {
            __builtin_amdgcn_s_sleep(1);
            if (++spins > (1L << 22)) break;  // safety valve
        }
        __atomic_signal_fence(__ATOMIC_ACQUIRE);
    }
    __syncthreads();
}

// ---------------- prepack (unchanged layouts) ----------------
// w1f: [ut 32][kb 18][gate 4][n 16][kk 32]  (gcol = gate*512 + ut*16 + n, k = kb*32+kk)
// w2f: [ut4 4][kb 18][gate 4][n 16][kk 32]  (gcol = gate*64 + ut4*16 + n)
__global__ void prep_kernel(const float* __restrict__ Wih1, const float* __restrict__ Whh1,
                            const float* __restrict__ Wih2, const float* __restrict__ Whh2,
                            const float* __restrict__ bih1, const float* __restrict__ bhh1,
                            const float* __restrict__ bih2, const float* __restrict__ bhh2,
                            short* __restrict__ h1g, short* __restrict__ h2g,
                            short* __restrict__ w1f, short* __restrict__ w2f,
                            float* __restrict__ bs1, float* __restrict__ bs2,
                            unsigned* __restrict__ bar) {
    const int i0 = blockIdx.x * blockDim.x + threadIdx.x;
    const int stride = gridDim.x * blockDim.x;
    for (int i = i0; i < 1024; i += stride) bar[i] = 0;                // 8 groups x 128
    for (int i = i0; i < 2 * Bn * Hn; i += stride) h1g[i] = 0;
    for (int i = i0; i < 2 * Bn * Fn; i += stride) h2g[i] = 0;
    for (int i = i0; i < 2048 * 576; i += stride) {
        int kk = i & 31, n = (i >> 5) & 15, ct = (i >> 9) & 3;
        int r = i >> 11; int kb = r % 18; int ut = r / 18;
        int gcol = ct * 512 + ut * 16 + n;
        int k = kb * 32 + kk;
        float v = (k < 64) ? Wih1[gcol * 64 + k] : Whh1[gcol * 512 + (k - 64)];
        w1f[i] = f2bf(v);
    }
    for (int i = i0; i < 256 * 576; i += stride) {
        int kk = i & 31, n = (i >> 5) & 15, ct = (i >> 9) & 3;
        int r = i >> 11; int kb = r % 18; int ut4 = r / 18;
        int gcol = ct * 64 + ut4 * 16 + n;
        int k = kb * 32 + kk;
        float v = (k < 512) ? Wih2[gcol * 512 + k] : Whh2[gcol * 64 + (k - 512)];
        w2f[i] = f2bf(v);
    }
    for (int i = i0; i < 2048; i += stride) bs1[i] = bih1[i] + bhh1[i];
    for (int i = i0; i < 256;  i += stride) bs2[i] = bih2[i] + bhh2[i];
}

// ---------------- main persistent kernel ----------------
// 144 blocks x 256 threads (4 waves), 1 block/CU, 1 wave/SIMD -> 512 unified-VGPR budget.
// Waves: wvr = wv&1 (row half: 32 rows), wvc = wv>>1 (col half: one 16-unit tile).
// Recurrent weights live in registers; per step, ALL recurrent-state loads are staged
// back-to-back into registers (one pipelined MALL latency) before any MFMA consumes
// them, and the x-part GEMM runs before the barrier wait (hidden under the spin).
__global__ __launch_bounds__(256, 1) void lstm_kernel(
    const float* __restrict__ data,
    const short* __restrict__ w1f, const float* __restrict__ bs1,
    const short* __restrict__ w2f, const float* __restrict__ bs2,
    short* __restrict__ h1g, short* __restrict__ c1g, short* __restrict__ h2g,
    float* __restrict__ out, unsigned* __restrict__ bar) {
    const int tid = threadIdx.x;
    const int lane = tid & 63, wv = tid >> 6;
    const int n = lane & 15, q = lane >> 4;
    const int wvr = wv & 1, wvc = wv >> 1;
    const int bid = blockIdx.x;
    const f32x4 Z4 = {0.f, 0.f, 0.f, 0.f};

    if (bid < NB1) {
        // ---------------- LSTM1 ----------------
        const int rt = bid >> 4, utp = bid & 15;
        const int ut = utp * 2 + wvc;
        const int rowbase = rt * 64 + wvr * 32;
        const int ucol = ut * 16 + n;
        unsigned* bcnt = bar + rt * 128;
        unsigned* bgen = bar + rt * 128 + 64;
        const float bi_ = bs1[ucol], bf_ = bs1[512 + ucol], bg_ = bs1[1024 + ucol], bo_ = bs1[1536 + ucol];
        const short* wbase = w1f + ut * 36864 + n * 32 + q * 8;
        const int r0 = rowbase + n, r1 = rowbase + 16 + n;

        // recurrent weights (kb 2..17) -> registers, once
        bf16x8 wr[16][4];
#pragma unroll
        for (int kb = 0; kb < 16; ++kb)
#pragma unroll
            for (int g = 0; g < 4; ++g)
                wr[kb][g] = *(const bf16x8*)(wbase + ((kb + 2) * 4 + g) * 512);

        f32x4 c1f[2]; c1f[0] = Z4; c1f[1] = Z4;

        for (int t = 0; t < Tn; ++t) {
            const short* h1r = h1g + (t & 1) * (Bn * Hn);
            short* h1w = h1g + ((t + 1) & 1) * (Bn * Hn);
            short* c1w = c1g + (t & 1) * (Bn * Hn);
            f32x4 acc[2][4];
#pragma unroll
            for (int a = 0; a < 2; ++a)
#pragma unroll
                for (int g = 0; g < 4; ++g) acc[a][g] = Z4;

            // ---- x part (kb 0,1): independent of peers -> runs BEFORE the wait,
            // its HBM/L2 latency hides under the barrier spin.
            const float* x0 = data + (size_t)r0 * 65536 + t * 64;
            const float* x1 = data + (size_t)r1 * 65536 + t * 64;
#pragma unroll
            for (int kb = 0; kb < 2; ++kb) {
                const bf16x8 a0 = cvt8(x0 + kb * 32 + q * 8);
                const bf16x8 a1 = cvt8(x1 + kb * 32 + q * 8);
#pragma unroll
                for (int g = 0; g < 4; ++g) {
                    const bf16x8 b = *(const bf16x8*)(wbase + (kb * 4 + g) * 512);
                    acc[0][g] = __builtin_amdgcn_mfma_f32_16x16x32_bf16(a0, b, acc[0][g], 0, 0, 0);
                    acc[1][g] = __builtin_amdgcn_mfma_f32_16x16x32_bf16(a1, b, acc[1][g], 0, 0, 0);
                }
            }

            bar_wait(bgen, (unsigned)t);   // peers finished step t-1 (trivial at t=0)

            // ---- h part (kb 2..17): stage ALL 64 MALL loads back-to-back, then MFMA.
            bf16x8 A0[16], A1[16];
#pragma unroll
            for (int kb = 0; kb < 16; ++kb) {
                const int k = kb * 32 + q * 8;
                A0[kb] = ld16B(h1r + r0 * 512 + k);
                A1[kb] = ld16B(h1r + r1 * 512 + k);
            }
            __builtin_amdgcn_sched_barrier(0);  // keep loads issued before the MFMA block
#pragma unroll
            for (int kb = 0; kb < 16; ++kb) {
#pragma unroll
                for (int g = 0; g < 4; ++g) {
                    acc[0][g] = __builtin_amdgcn_mfma_f32_16x16x32_bf16(A0[kb], wr[kb][g], acc[0][g], 0, 0, 0);
                    acc[1][g] = __builtin_amdgcn_mfma_f32_16x16x32_bf16(A1[kb], wr[kb][g], acc[1][g], 0, 0, 0);
                }
            }

            // epilogue: C-frag col = lane&15 (unit), row = q*4 + reg
#pragma unroll
            for (int rt16 = 0; rt16 < 2; ++rt16) {
#pragma unroll
                for (int r = 0; r < 4; ++r) {
                    const float xi = acc[rt16][0][r] + bi_;
                    const float xf = acc[rt16][1][r] + bf_;
                    const float xg = acc[rt16][2][r] + bg_;
                    const float xo = acc[rt16][3][r] + bo_;
                    const float ii = sigm(xi), ff = sigm(xf), gg = tanh_(xg), oo = sigm(xo);
                    const float c = ff * c1f[rt16][r] + ii * gg;
                    c1f[rt16][r] = c;
                    const float h = oo * tanh_(c);
                    const int row = rowbase + rt16 * 16 + q * 4 + r;
                    st2(h1w + row * 512 + ucol, f2bf(h));
                    st2(c1w + row * 512 + ucol, f2bf(c));
                }
            }
            bar_arrive(bcnt, bgen, (unsigned)(t + 1));
        }
    } else {
        // ---------------- LSTM2 ----------------
        const int b2 = bid - NB1;
        const int rt2 = b2 >> 1, u2 = b2 & 1;
        const int ut4 = u2 * 2 + wvc;
        const int rowbase = rt2 * 64 + wvr * 32;
        const int ucol = ut4 * 16 + n;
        unsigned* bcnt = bar + rt2 * 128;
        unsigned* bgen = bar + rt2 * 128 + 64;
        const float bi_ = bs2[ucol], bf_ = bs2[64 + ucol], bg_ = bs2[128 + ucol], bo_ = bs2[192 + ucol];
        const short* wbase = w2f + ut4 * 36864 + n * 32 + q * 8;
        const int r0 = rowbase + n, r1 = rowbase + 16 + n;

        // c1-part weights (kb 0..15) -> registers
        bf16x8 wr[16][4];
#pragma unroll
        for (int kb = 0; kb < 16; ++kb)
#pragma unroll
            for (int g = 0; g < 4; ++g)
                wr[kb][g] = *(const bf16x8*)(wbase + (kb * 4 + g) * 512);

        f32x4 c2f[2]; c2f[0] = Z4; c2f[1] = Z4;

        for (int t = 0; t < Tn; ++t) {
            bar_arrive(bcnt, bgen, (unsigned)(t + 1));  // signals: finished step t-1
            bar_wait(bgen, (unsigned)(t + 1));          // wait for c1(t)
            const short* c1r = c1g + (t & 1) * (Bn * Hn);
            const short* h2r = h2g + (t & 1) * (Bn * Fn);
            short* h2w = h2g + ((t + 1) & 1) * (Bn * Fn);
            f32x4 acc[2][4];
#pragma unroll
            for (int a = 0; a < 2; ++a)
#pragma unroll
                for (int g = 0; g < 4; ++g) acc[a][g] = Z4;

            // ---- stage ALL state loads (c1: 64, h2: 8) + streamed tail weights.
            bf16x8 A0[16], A1[16];
#pragma unroll
            for (int kb = 0; kb < 16; ++kb) {
                const int k = kb * 32 + q * 8;
                A0[kb] = ld16B(c1r + r0 * 512 + k);
                A1[kb] = ld16B(c1r + r1 * 512 + k);
            }
            bf16x8 H0[2], H1[2], wh[2][4];
#pragma unroll
            for (int kb = 0; kb < 2; ++kb) {
                const int k = kb * 32 + q * 8;
                H0[kb] = ld16B(h2r + r0 * 64 + k);
                H1[kb] = ld16B(h2r + r1 * 64 + k);
#pragma unroll
                for (int g = 0; g < 4; ++g)
                    wh[kb][g] = *(const bf16x8*)(wbase + ((kb + 16) * 4 + g) * 512);
            }
            __builtin_amdgcn_sched_barrier(0);
#pragma unroll
            for (int kb = 0; kb < 16; ++kb) {
#pragma unroll
                for (int g = 0; g < 4; ++g) {
                    acc[0][g] = __builtin_amdgcn_mfma_f32_16x16x32_bf16(A0[kb], wr[kb][g], acc[0][g], 0, 0, 0);
                    acc[1][g] = __builtin_amdgcn_mfma_f32_16x16x32_bf16(A1[kb], wr[kb][g], acc[1][g], 0, 0, 0);
                }
            }
#pragma unroll
            for (int kb = 0; kb < 2; ++kb) {
#pragma unroll
                for (int g = 0; g < 4; ++g) {
                    acc[0][g] = __builtin_amdgcn_mfma_f32_16x16x32_bf16(H0[kb], wh[kb][g], acc[0][g], 0, 0, 0);
                    acc[1][g] = __builtin_amdgcn_mfma_f32_16x16x32_bf16(H1[kb], wh[kb][g], acc[1][g], 0, 0, 0);
                }
            }
#pragma unroll
            for (int rt16 = 0; rt16 < 2; ++rt16) {
#pragma unroll
                for (int r = 0; r < 4; ++r) {
                    const float xi = acc[rt16][0][r] + bi_;
                    const float xf = acc[rt16][1][r] + bf_;
                    const float xg = acc[rt16][2][r] + bg_;
                    const float xo = acc[rt16][3][r] + bo_;
                    const float ii = sigm(xi), ff = sigm(xf), gg = tanh_(xg), oo = sigm(xo);
                    const float c = ff * c2f[rt16][r] + ii * gg;
                    c2f[rt16][r] = c;
                    const float h = oo * tanh_(c);
                    const int row = rowbase + rt16 * 16 + q * 4 + r;
                    out[(size_t)row * 65536 + (size_t)t * 64 + ucol] = c;  // output is c2
                    st2(h2w + row * 64 + ucol, f2bf(h));
                }
            }
        }
    }
}

extern "C" void kernel_launch(void* const* d_in, const int* in_sizes, int n_in,
                              void* d_out, int out_size, void* d_ws, size_t ws_size,
                              hipStream_t stream) {
    const float* data = (const float*)d_in[0];
    const float* Wih1 = (const float*)d_in[1];
    const float* Whh1 = (const float*)d_in[2];
    const float* bih1 = (const float*)d_in[3];
    const float* bhh1 = (const float*)d_in[4];
    const float* Wih2 = (const float*)d_in[5];
    const float* Whh2 = (const float*)d_in[6];
    const float* bih2 = (const float*)d_in[7];
    const float* bhh2 = (const float*)d_in[8];
    float* out = (float*)d_out;

    char* w = (char*)d_ws;
    short* h1g = (short*)(w + 0);          // 2 * 512*512*2 = 1,048,576
    short* c1g = (short*)(w + 1048576);    // 1,048,576
    short* h2g = (short*)(w + 2097152);    // 2 * 512*64*2 = 131,072
    short* w2f = (short*)(w + 2228224);    // 256*576*2 = 294,912
    short* w1f = (short*)(w + 2523136);    // 2048*576*2 = 2,359,296
    float* bs1 = (float*)(w + 4882432);    // 8,192
    float* bs2 = (float*)(w + 4890624);    // 1,024
    unsigned* bar = (unsigned*)(w + 4891648); // 4 KB: 8 groups x 512 B

    hipLaunchKernelGGL(prep_kernel, dim3(1024), dim3(256), 0, stream,
                       Wih1, Whh1, Wih2, Whh2, bih1, bhh1, bih2, bhh2,
                       h1g, h2g, w1f, w2f, bs1, bs2, bar);

    hipLaunchKernelGGL(lstm_kernel, dim3(NBLK), dim3(256), 0, stream,
                       data, w1f, bs1, w2f, bs2, h1g, c1g, h2g, out, bar);
}

// Round 2
// 13518.152 us; speedup vs baseline: 1.2008x; 1.2008x over previous
//
#include <hip/hip_runtime.h>

// Problem constants
#define Bn   512
#define Tn   1024
#define Fn   64
#define Hn   512
#define NB1  128                 // LSTM1 blocks: 8 rt x 16 utp
#define NB2  16                  // LSTM2 blocks: 8 rt x 2 u2
#define NBLK (NB1 + NB2)
#define GMEM 18                  // barrier members per rt group: 16 + 2

typedef short bf16x8 __attribute__((ext_vector_type(8)));
typedef float f32x4  __attribute__((ext_vector_type(4)));

__device__ __forceinline__ short f2bf(float f) {
    union { float f; unsigned u; } v; v.f = f;
    unsigned r = (v.u + 0x7FFFu + ((v.u >> 16) & 1u)) >> 16;  // RNE
    return (short)(unsigned short)r;
}
__device__ __forceinline__ float sigm(float x) { return 1.f / (1.f + __expf(-x)); }
__device__ __forceinline__ float tanh_(float x) { return 2.f / (1.f + __expf(-2.f * x)) - 1.f; }

__device__ __forceinline__ bf16x8 cvt8(const float* p) {
    const float4 v0 = *(const float4*)p;
    const float4 v1 = *(const float4*)(p + 4);
    bf16x8 a;
    a[0] = f2bf(v0.x); a[1] = f2bf(v0.y); a[2] = f2bf(v0.z); a[3] = f2bf(v0.w);
    a[4] = f2bf(v1.x); a[5] = f2bf(v1.y); a[6] = f2bf(v1.z); a[7] = f2bf(v1.w);
    return a;
}

// -------- device-coherent (MALL-level) state exchange: relaxed agent atomics --------
// Bypass the (non-coherent) per-XCD L2 entirely: no acquire/invalidate needed, and
// the L2-cached weights/x stay resident across all 1024 steps.
__device__ __forceinline__ unsigned long long ld64(const short* p) {
    return __hip_atomic_load((const unsigned long long*)p, __ATOMIC_RELAXED, __HIP_MEMORY_SCOPE_AGENT);
}
__device__ __forceinline__ bf16x8 ld16B(const short* p) {
    union { unsigned long long u[2]; bf16x8 v; } x;
    x.u[0] = ld64(p);
    x.u[1] = ld64(p + 4);
    return x.v;
}
__device__ __forceinline__ void st2(short* p, short v) {
    __hip_atomic_store((unsigned short*)p, (unsigned short)v, __ATOMIC_RELAXED, __HIP_MEMORY_SCOPE_AGENT);
}

// Single monotonic-counter barrier per rt group. An arrival's fetch_add(release)
// IS the publication of that block's state stores (no separate gen store: one
// fewer MALL round trip on the critical path). Each of the 18 members arrives
// exactly once per generation and only after observing the previous generation
// complete, so cnt >= 18*g  <=>  all generation-g arrivals have landed.
__device__ __forceinline__ void bar_arrive(unsigned* cnt) {
    __syncthreads();   // all waves' state stores drained before thread 0 releases
    if (threadIdx.x == 0)
        (void)__hip_atomic_fetch_add(cnt, 1u, __ATOMIC_RELEASE, __HIP_MEMORY_SCOPE_AGENT);
}
__device__ __forceinline__ void bar_wait(unsigned* cnt, unsigned need) {
    if (threadIdx.x == 0) {
        long spins = 0;
        while (__hip_atomic_load(cnt, __ATOMIC_RELAXED, __HIP_MEMORY_SCOPE_AGENT) < need) {
            __builtin_amdgcn_s_sleep(1);
            if (++spins > (1L << 22)) break;  // safety valve
        }
        __atomic_signal_fence(__ATOMIC_ACQUIRE);
    }
    __syncthreads();
}

// ---------------- prepack (unchanged layouts) ----------------
// w1f: [ut 32][kb 18][gate 4][n 16][kk 32]  (gcol = gate*512 + ut*16 + n, k = kb*32+kk)
// w2f: [ut4 4][kb 18][gate 4][n 16][kk 32]  (gcol = gate*64 + ut4*16 + n)
__global__ void prep_kernel(const float* __restrict__ Wih1, const float* __restrict__ Whh1,
                            const float* __restrict__ Wih2, const float* __restrict__ Whh2,
                            const float* __restrict__ bih1, const float* __restrict__ bhh1,
                            const float* __restrict__ bih2, const float* __restrict__ bhh2,
                            short* __restrict__ h1g, short* __restrict__ h2g,
                            short* __restrict__ w1f, short* __restrict__ w2f,
                            float* __restrict__ bs1, float* __restrict__ bs2,
                            unsigned* __restrict__ bar) {
    const int i0 = blockIdx.x * blockDim.x + threadIdx.x;
    const int stride = gridDim.x * blockDim.x;
    for (int i = i0; i < 1024; i += stride) bar[i] = 0;                // 8 groups x 128
    for (int i = i0; i < 2 * Bn * Hn; i += stride) h1g[i] = 0;
    for (int i = i0; i < 2 * Bn * Fn; i += stride) h2g[i] = 0;
    for (int i = i0; i < 2048 * 576; i += stride) {
        int kk = i & 31, n = (i >> 5) & 15, ct = (i >> 9) & 3;
        int r = i >> 11; int kb = r % 18; int ut = r / 18;
        int gcol = ct * 512 + ut * 16 + n;
        int k = kb * 32 + kk;
        float v = (k < 64) ? Wih1[gcol * 64 + k] : Whh1[gcol * 512 + (k - 64)];
        w1f[i] = f2bf(v);
    }
    for (int i = i0; i < 256 * 576; i += stride) {
        int kk = i & 31, n = (i >> 5) & 15, ct = (i >> 9) & 3;
        int r = i >> 11; int kb = r % 18; int ut4 = r / 18;
        int gcol = ct * 64 + ut4 * 16 + n;
        int k = kb * 32 + kk;
        float v = (k < 512) ? Wih2[gcol * 512 + k] : Whh2[gcol * 64 + (k - 512)];
        w2f[i] = f2bf(v);
    }
    for (int i = i0; i < 2048; i += stride) bs1[i] = bih1[i] + bhh1[i];
    for (int i = i0; i < 256;  i += stride) bs2[i] = bih2[i] + bhh2[i];
}

// ---------------- main persistent kernel ----------------
// 144 blocks x 256 threads (4 waves), 1 block/CU, 1 wave/SIMD -> 512 unified-VGPR budget.
// Waves: wvr = wv&1 (row half: 32 rows), wvc = wv>>1 (col half: one 16-unit tile).
// Split-barrier schedule (the R2 change): LSTM2 arrives BEFORE waiting and LSTM1
// computes its x-part GEMM before waiting, so LSTM1(t+1) overlaps LSTM2(t).
// h-part loads stay interleaved with MFMAs (R0 style: compiler pipelines them;
// explicit staging blew the register budget in R1).
__global__ __launch_bounds__(256, 1) void lstm_kernel(
    const float* __restrict__ data,
    const short* __restrict__ w1f, const float* __restrict__ bs1,
    const short* __restrict__ w2f, const float* __restrict__ bs2,
    short* __restrict__ h1g, short* __restrict__ c1g, short* __restrict__ h2g,
    float* __restrict__ out, unsigned* __restrict__ bar) {
    const int tid = threadIdx.x;
    const int lane = tid & 63, wv = tid >> 6;
    const int n = lane & 15, q = lane >> 4;
    const int wvr = wv & 1, wvc = wv >> 1;
    const int bid = blockIdx.x;
    const f32x4 Z4 = {0.f, 0.f, 0.f, 0.f};

    if (bid < NB1) {
        // ---------------- LSTM1 ----------------
        const int rt = bid >> 4, utp = bid & 15;
        const int ut = utp * 2 + wvc;
        const int rowbase = rt * 64 + wvr * 32;
        const int ucol = ut * 16 + n;
        unsigned* bcnt = bar + rt * 128;
        const float bi_ = bs1[ucol], bf_ = bs1[512 + ucol], bg_ = bs1[1024 + ucol], bo_ = bs1[1536 + ucol];
        const short* wbase = w1f + ut * 36864 + n * 32 + q * 8;
        const int r0 = rowbase + n, r1 = rowbase + 16 + n;

        // recurrent weights (kb 2..17) -> registers, once
        bf16x8 wr[16][4];
#pragma unroll
        for (int kb = 0; kb < 16; ++kb)
#pragma unroll
            for (int g = 0; g < 4; ++g)
                wr[kb][g] = *(const bf16x8*)(wbase + ((kb + 2) * 4 + g) * 512);

        f32x4 c1f[2]; c1f[0] = Z4; c1f[1] = Z4;

        for (int t = 0; t < Tn; ++t) {
            const short* h1r = h1g + (t & 1) * (Bn * Hn);
            short* h1w = h1g + ((t + 1) & 1) * (Bn * Hn);
            short* c1w = c1g + (t & 1) * (Bn * Hn);
            f32x4 acc[2][4];
#pragma unroll
            for (int a = 0; a < 2; ++a)
#pragma unroll
                for (int g = 0; g < 4; ++g) acc[a][g] = Z4;

            // ---- x part (kb 0,1): independent of peers -> runs BEFORE the wait,
            // its HBM/L2 latency hides under the barrier spin.
            const float* x0 = data + (size_t)r0 * 65536 + t * 64;
            const float* x1 = data + (size_t)r1 * 65536 + t * 64;
#pragma unroll
            for (int kb = 0; kb < 2; ++kb) {
                const bf16x8 a0 = cvt8(x0 + kb * 32 + q * 8);
                const bf16x8 a1 = cvt8(x1 + kb * 32 + q * 8);
#pragma unroll
                for (int g = 0; g < 4; ++g) {
                    const bf16x8 b = *(const bf16x8*)(wbase + (kb * 4 + g) * 512);
                    acc[0][g] = __builtin_amdgcn_mfma_f32_16x16x32_bf16(a0, b, acc[0][g], 0, 0, 0);
                    acc[1][g] = __builtin_amdgcn_mfma_f32_16x16x32_bf16(a1, b, acc[1][g], 0, 0, 0);
                }
            }

            bar_wait(bcnt, (unsigned)(GMEM * t));   // peers finished step t-1

            // ---- h part (kb 2..17): interleaved loads + MFMA (compiler pipelines)
#pragma unroll
            for (int kb = 0; kb < 16; ++kb) {
                const int k = kb * 32 + q * 8;
                const bf16x8 a0 = ld16B(h1r + r0 * 512 + k);
                const bf16x8 a1 = ld16B(h1r + r1 * 512 + k);
#pragma unroll
                for (int g = 0; g < 4; ++g) {
                    acc[0][g] = __builtin_amdgcn_mfma_f32_16x16x32_bf16(a0, wr[kb][g], acc[0][g], 0, 0, 0);
                    acc[1][g] = __builtin_amdgcn_mfma_f32_16x16x32_bf16(a1, wr[kb][g], acc[1][g], 0, 0, 0);
                }
            }

            // epilogue: C-frag col = lane&15 (unit), row = q*4 + reg
#pragma unroll
            for (int rt16 = 0; rt16 < 2; ++rt16) {
#pragma unroll
                for (int r = 0; r < 4; ++r) {
                    const float xi = acc[rt16][0][r] + bi_;
                    const float xf = acc[rt16][1][r] + bf_;
                    const float xg = acc[rt16][2][r] + bg_;
                    const float xo = acc[rt16][3][r] + bo_;
                    const float ii = sigm(xi), ff = sigm(xf), gg = tanh_(xg), oo = sigm(xo);
                    const float c = ff * c1f[rt16][r] + ii * gg;
                    c1f[rt16][r] = c;
                    const float h = oo * tanh_(c);
                    const int row = rowbase + rt16 * 16 + q * 4 + r;
                    st2(h1w + row * 512 + ucol, f2bf(h));
                    st2(c1w + row * 512 + ucol, f2bf(c));
                }
            }
            bar_arrive(bcnt);   // publishes h1(t), c1(t); counts toward gen t+1
        }
    } else {
        // ---------------- LSTM2 ----------------
        const int b2 = bid - NB1;
        const int rt2 = b2 >> 1, u2 = b2 & 1;
        const int ut4 = u2 * 2 + wvc;
        const int rowbase = rt2 * 64 + wvr * 32;
        const int ucol = ut4 * 16 + n;
        unsigned* bcnt = bar + rt2 * 128;
        const float bi_ = bs2[ucol], bf_ = bs2[64 + ucol], bg_ = bs2[128 + ucol], bo_ = bs2[192 + ucol];
        const short* wbase = w2f + ut4 * 36864 + n * 32 + q * 8;
        const int r0 = rowbase + n, r1 = rowbase + 16 + n;

        // c1-part weights (kb 0..15) -> registers
        bf16x8 wr[16][4];
#pragma unroll
        for (int kb = 0; kb < 16; ++kb)
#pragma unroll
            for (int g = 0; g < 4; ++g)
                wr[kb][g] = *(const bf16x8*)(wbase + (kb * 4 + g) * 512);

        f32x4 c2f[2]; c2f[0] = Z4; c2f[1] = Z4;

        for (int t = 0; t < Tn; ++t) {
            bar_arrive(bcnt);                             // publishes h2(t-1); counts toward gen t+1
            bar_wait(bcnt, (unsigned)(GMEM * (t + 1)));   // wait for c1(t)
            const short* c1r = c1g + (t & 1) * (Bn * Hn);
            const short* h2r = h2g + (t & 1) * (Bn * Fn);
            short* h2w = h2g + ((t + 1) & 1) * (Bn * Fn);
            f32x4 acc[2][4];
#pragma unroll
            for (int a = 0; a < 2; ++a)
#pragma unroll
                for (int g = 0; g < 4; ++g) acc[a][g] = Z4;

#pragma unroll
            for (int kb = 0; kb < 16; ++kb) {
                const int k = kb * 32 + q * 8;
                const bf16x8 a0 = ld16B(c1r + r0 * 512 + k);
                const bf16x8 a1 = ld16B(c1r + r1 * 512 + k);
#pragma unroll
                for (int g = 0; g < 4; ++g) {
                    acc[0][g] = __builtin_amdgcn_mfma_f32_16x16x32_bf16(a0, wr[kb][g], acc[0][g], 0, 0, 0);
                    acc[1][g] = __builtin_amdgcn_mfma_f32_16x16x32_bf16(a1, wr[kb][g], acc[1][g], 0, 0, 0);
                }
            }
#pragma unroll
            for (int kb = 16; kb < 18; ++kb) {
                const int k = (kb - 16) * 32 + q * 8;
                const bf16x8 a0 = ld16B(h2r + r0 * 64 + k);
                const bf16x8 a1 = ld16B(h2r + r1 * 64 + k);
#pragma unroll
                for (int g = 0; g < 4; ++g) {
                    const bf16x8 b = *(const bf16x8*)(wbase + (kb * 4 + g) * 512);
                    acc[0][g] = __builtin_amdgcn_mfma_f32_16x16x32_bf16(a0, b, acc[0][g], 0, 0, 0);
                    acc[1][g] = __builtin_amdgcn_mfma_f32_16x16x32_bf16(a1, b, acc[1][g], 0, 0, 0);
                }
            }
#pragma unroll
            for (int rt16 = 0; rt16 < 2; ++rt16) {
#pragma unroll
                for (int r = 0; r < 4; ++r) {
                    const float xi = acc[rt16][0][r] + bi_;
                    const float xf = acc[rt16][1][r] + bf_;
                    const float xg = acc[rt16][2][r] + bg_;
                    const float xo = acc[rt16][3][r] + bo_;
                    const float ii = sigm(xi), ff = sigm(xf), gg = tanh_(xg), oo = sigm(xo);
                    const float c = ff * c2f[rt16][r] + ii * gg;
                    c2f[rt16][r] = c;
                    const float h = oo * tanh_(c);
                    const int row = rowbase + rt16 * 16 + q * 4 + r;
                    out[(size_t)row * 65536 + (size_t)t * 64 + ucol] = c;  // output is c2
                    st2(h2w + row * 64 + ucol, f2bf(h));
                }
            }
        }
    }
}

extern "C" void kernel_launch(void* const* d_in, const int* in_sizes, int n_in,
                              void* d_out, int out_size, void* d_ws, size_t ws_size,
                              hipStream_t stream) {
    const float* data = (const float*)d_in[0];
    const float* Wih1 = (const float*)d_in[1];
    const float* Whh1 = (const float*)d_in[2];
    const float* bih1 = (const float*)d_in[3];
    const float* bhh1 = (const float*)d_in[4];
    const float* Wih2 = (const float*)d_in[5];
    const float* Whh2 = (const float*)d_in[6];
    const float* bih2 = (const float*)d_in[7];
    const float* bhh2 = (const float*)d_in[8];
    float* out = (float*)d_out;

    char* w = (char*)d_ws;
    short* h1g = (short*)(w + 0);          // 2 * 512*512*2 = 1,048,576
    short* c1g = (short*)(w + 1048576);    // 1,048,576
    short* h2g = (short*)(w + 2097152);    // 2 * 512*64*2 = 131,072
    short* w2f = (short*)(w + 2228224);    // 256*576*2 = 294,912
    short* w1f = (short*)(w + 2523136);    // 2048*576*2 = 2,359,296
    float* bs1 = (float*)(w + 4882432);    // 8,192
    float* bs2 = (float*)(w + 4890624);    // 1,024
    unsigned* bar = (unsigned*)(w + 4891648); // 4 KB: 8 groups x 512 B

    hipLaunchKernelGGL(prep_kernel, dim3(1024), dim3(256), 0, stream,
                       Wih1, Whh1, Wih2, Whh2, bih1, bhh1, bih2, bhh2,
                       h1g, h2g, w1f, w2f, bs1, bs2, bar);

    hipLaunchKernelGGL(lstm_kernel, dim3(NBLK), dim3(256), 0, stream,
                       data, w1f, bs1, w2f, bs2, h1g, c1g, h2g, out, bar);
}

// Round 3
// 13420.111 us; speedup vs baseline: 1.2096x; 1.0073x over previous
//
#include <hip/hip_runtime.h>

// Problem constants
#define Bn   512
#define Tn   1024
#define Fn   64
#define Hn   512
#define NB1  128                 // LSTM1 blocks: 8 rt x 16 utp
#define NB2  16                  // LSTM2 blocks: 8 rt x 2 u2
#define NBLK (NB1 + NB2)
#define GMEM 18                  // barrier members per rt group: 16 L1 + 2 L2

typedef short bf16x8 __attribute__((ext_vector_type(8)));
typedef float f32x4  __attribute__((ext_vector_type(4)));

__device__ __forceinline__ short f2bf(float f) {
    union { float f; unsigned u; } v; v.f = f;
    unsigned r = (v.u + 0x7FFFu + ((v.u >> 16) & 1u)) >> 16;  // RNE
    return (short)(unsigned short)r;
}
__device__ __forceinline__ float sigm(float x) { return 1.f / (1.f + __expf(-x)); }
__device__ __forceinline__ float tanh_(float x) { return 2.f / (1.f + __expf(-2.f * x)) - 1.f; }

__device__ __forceinline__ bf16x8 cvt8(const float* p) {
    const float4 v0 = *(const float4*)p;
    const float4 v1 = *(const float4*)(p + 4);
    bf16x8 a;
    a[0] = f2bf(v0.x); a[1] = f2bf(v0.y); a[2] = f2bf(v0.z); a[3] = f2bf(v0.w);
    a[4] = f2bf(v1.x); a[5] = f2bf(v1.y); a[6] = f2bf(v1.z); a[7] = f2bf(v1.w);
    return a;
}

// -------- device-coherent (MALL-level) state exchange: relaxed agent atomics --------
// Bypass the (non-coherent) per-XCD L2 entirely: no acquire/invalidate needed, and
// the L2-cached weights/x stay resident across all 1024 steps.
__device__ __forceinline__ unsigned long long ld64(const short* p) {
    return __hip_atomic_load((const unsigned long long*)p, __ATOMIC_RELAXED, __HIP_MEMORY_SCOPE_AGENT);
}
__device__ __forceinline__ bf16x8 ld16B(const short* p) {
    union { unsigned long long u[2]; bf16x8 v; } x;
    x.u[0] = ld64(p);
    x.u[1] = ld64(p + 4);
    return x.v;
}
__device__ __forceinline__ void st2(short* p, short v) {
    __hip_atomic_store((unsigned short*)p, (unsigned short)v, __ATOMIC_RELAXED, __HIP_MEMORY_SCOPE_AGENT);
}

// ---- per-member flag barrier (NO same-address RMWs: stores to distinct words) ----
// flags[m] = number of iterations member m has completed (published with release
// after that iteration's state stores are drained by __syncthreads' vmcnt(0)).
// Waiters: lanes 0..17 of EVERY wave each poll one member flag in parallel; one
// MALL round trip per poll iteration. No post-wait __syncthreads needed.
__device__ __forceinline__ void flag_arrive(int* slot, int val) {
    __syncthreads();   // every wave drains vmcnt(0) before s_barrier -> stores visible
    if (threadIdx.x == 0)
        __hip_atomic_store(slot, val, __ATOMIC_RELEASE, __HIP_MEMORY_SCOPE_AGENT);
}
// lanes 0..15 wait for L1 flags >= tgtA; lanes 16..17 wait for L2 flags >= tgtB
__device__ __forceinline__ void flag_wait(const int* flags, int tgtA, int tgtB) {
    const int lane = threadIdx.x & 63;
    const int tgt = (lane < 16) ? tgtA : tgtB;
    long spins = 0;
    for (;;) {
        bool ok = (lane >= GMEM) ||
            (__hip_atomic_load(flags + lane, __ATOMIC_RELAXED, __HIP_MEMORY_SCOPE_AGENT) >= tgt);
        if (__all(ok)) break;
        if (++spins > (1L << 21)) break;   // safety valve
        __builtin_amdgcn_s_sleep(1);
    }
    __atomic_signal_fence(__ATOMIC_ACQUIRE);
}

// ---------------- prepack (unchanged layouts) ----------------
// w1f: [ut 32][kb 18][gate 4][n 16][kk 32]  (gcol = gate*512 + ut*16 + n, k = kb*32+kk)
// w2f: [ut4 4][kb 18][gate 4][n 16][kk 32]  (gcol = gate*64 + ut4*16 + n)
__global__ void prep_kernel(const float* __restrict__ Wih1, const float* __restrict__ Whh1,
                            const float* __restrict__ Wih2, const float* __restrict__ Whh2,
                            const float* __restrict__ bih1, const float* __restrict__ bhh1,
                            const float* __restrict__ bih2, const float* __restrict__ bhh2,
                            short* __restrict__ h1g, short* __restrict__ h2g,
                            short* __restrict__ w1f, short* __restrict__ w2f,
                            float* __restrict__ bs1, float* __restrict__ bs2,
                            unsigned* __restrict__ bar) {
    const int i0 = blockIdx.x * blockDim.x + threadIdx.x;
    const int stride = gridDim.x * blockDim.x;
    for (int i = i0; i < 1024; i += stride) bar[i] = 0;                // 8 groups x 32 words (padded)
    for (int i = i0; i < 2 * Bn * Hn; i += stride) h1g[i] = 0;
    for (int i = i0; i < 2 * Bn * Fn; i += stride) h2g[i] = 0;
    for (int i = i0; i < 2048 * 576; i += stride) {
        int kk = i & 31, n = (i >> 5) & 15, ct = (i >> 9) & 3;
        int r = i >> 11; int kb = r % 18; int ut = r / 18;
        int gcol = ct * 512 + ut * 16 + n;
        int k = kb * 32 + kk;
        float v = (k < 64) ? Wih1[gcol * 64 + k] : Whh1[gcol * 512 + (k - 64)];
        w1f[i] = f2bf(v);
    }
    for (int i = i0; i < 256 * 576; i += stride) {
        int kk = i & 31, n = (i >> 5) & 15, ct = (i >> 9) & 3;
        int r = i >> 11; int kb = r % 18; int ut4 = r / 18;
        int gcol = ct * 64 + ut4 * 16 + n;
        int k = kb * 32 + kk;
        float v = (k < 512) ? Wih2[gcol * 512 + k] : Whh2[gcol * 64 + (k - 512)];
        w2f[i] = f2bf(v);
    }
    for (int i = i0; i < 2048; i += stride) bs1[i] = bih1[i] + bhh1[i];
    for (int i = i0; i < 256;  i += stride) bs2[i] = bih2[i] + bhh2[i];
}

// ---------------- main persistent kernel ----------------
// 144 blocks x 256 threads (4 waves), 1 block/CU, 1 wave/SIMD -> 512 unified-VGPR budget.
// Waves: wvr = wv&1 (row half: 32 rows), wvc = wv>>1 (col half: one 16-unit tile).
// Dependence encoding via per-member flags (flag = completed iterations):
//   L1 iter t: needs L1 flags >= t   (h1(t-1)), L2 flags >= t-1 (WAR on c1[t&1])
//   L2 iter t: needs L1 flags >= t+1 (c1(t)),   L2 flags >= t   (h2(t-1), WAR h2)
// So L2 runs one step behind L1 and stays OFF L1's critical path.
__global__ __launch_bounds__(256, 1) void lstm_kernel(
    const float* __restrict__ data,
    const short* __restrict__ w1f, const float* __restrict__ bs1,
    const short* __restrict__ w2f, const float* __restrict__ bs2,
    short* __restrict__ h1g, short* __restrict__ c1g, short* __restrict__ h2g,
    float* __restrict__ out, int* __restrict__ bar) {
    const int tid = threadIdx.x;
    const int lane = tid & 63, wv = tid >> 6;
    const int n = lane & 15, q = lane >> 4;
    const int wvr = wv & 1, wvc = wv >> 1;
    const int bid = blockIdx.x;
    const f32x4 Z4 = {0.f, 0.f, 0.f, 0.f};

    if (bid < NB1) {
        // ---------------- LSTM1 ----------------
        const int rt = bid >> 4, utp = bid & 15;
        const int ut = utp * 2 + wvc;
        const int rowbase = rt * 64 + wvr * 32;
        const int ucol = ut * 16 + n;
        int* grp = bar + rt * 32;           // 18 member flags (padded to 32 words)
        const float bi_ = bs1[ucol], bf_ = bs1[512 + ucol], bg_ = bs1[1024 + ucol], bo_ = bs1[1536 + ucol];
        const short* wbase = w1f + ut * 36864 + n * 32 + q * 8;
        const int r0 = rowbase + n, r1 = rowbase + 16 + n;

        // recurrent weights (kb 2..17) -> registers, once
        bf16x8 wr[16][4];
#pragma unroll
        for (int kb = 0; kb < 16; ++kb)
#pragma unroll
            for (int g = 0; g < 4; ++g)
                wr[kb][g] = *(const bf16x8*)(wbase + ((kb + 2) * 4 + g) * 512);

        f32x4 c1f[2]; c1f[0] = Z4; c1f[1] = Z4;

        for (int t = 0; t < Tn; ++t) {
            const short* h1r = h1g + (t & 1) * (Bn * Hn);
            short* h1w = h1g + ((t + 1) & 1) * (Bn * Hn);
            short* c1w = c1g + (t & 1) * (Bn * Hn);
            f32x4 acc[2][4];
#pragma unroll
            for (int a = 0; a < 2; ++a)
#pragma unroll
                for (int g = 0; g < 4; ++g) acc[a][g] = Z4;

            // ---- x part (kb 0,1): independent of peers -> runs BEFORE the wait,
            // its HBM/L2 latency hides under the flag spin.
            const float* x0 = data + (size_t)r0 * 65536 + t * 64;
            const float* x1 = data + (size_t)r1 * 65536 + t * 64;
#pragma unroll
            for (int kb = 0; kb < 2; ++kb) {
                const bf16x8 a0 = cvt8(x0 + kb * 32 + q * 8);
                const bf16x8 a1 = cvt8(x1 + kb * 32 + q * 8);
#pragma unroll
                for (int g = 0; g < 4; ++g) {
                    const bf16x8 b = *(const bf16x8*)(wbase + (kb * 4 + g) * 512);
                    acc[0][g] = __builtin_amdgcn_mfma_f32_16x16x32_bf16(a0, b, acc[0][g], 0, 0, 0);
                    acc[1][g] = __builtin_amdgcn_mfma_f32_16x16x32_bf16(a1, b, acc[1][g], 0, 0, 0);
                }
            }

            flag_wait(grp, t, t - 1);   // peers' h1(t-1); L2 done with c1[t&1]

            // ---- h part (kb 2..17): interleaved loads + MFMA (compiler pipelines)
#pragma unroll
            for (int kb = 0; kb < 16; ++kb) {
                const int k = kb * 32 + q * 8;
                const bf16x8 a0 = ld16B(h1r + r0 * 512 + k);
                const bf16x8 a1 = ld16B(h1r + r1 * 512 + k);
#pragma unroll
                for (int g = 0; g < 4; ++g) {
                    acc[0][g] = __builtin_amdgcn_mfma_f32_16x16x32_bf16(a0, wr[kb][g], acc[0][g], 0, 0, 0);
                    acc[1][g] = __builtin_amdgcn_mfma_f32_16x16x32_bf16(a1, wr[kb][g], acc[1][g], 0, 0, 0);
                }
            }

            // epilogue: C-frag col = lane&15 (unit), row = q*4 + reg
#pragma unroll
            for (int rt16 = 0; rt16 < 2; ++rt16) {
#pragma unroll
                for (int r = 0; r < 4; ++r) {
                    const float xi = acc[rt16][0][r] + bi_;
                    const float xf = acc[rt16][1][r] + bf_;
                    const float xg = acc[rt16][2][r] + bg_;
                    const float xo = acc[rt16][3][r] + bo_;
                    const float ii = sigm(xi), ff = sigm(xf), gg = tanh_(xg), oo = sigm(xo);
                    const float c = ff * c1f[rt16][r] + ii * gg;
                    c1f[rt16][r] = c;
                    const float h = oo * tanh_(c);
                    const int row = rowbase + rt16 * 16 + q * 4 + r;
                    st2(h1w + row * 512 + ucol, f2bf(h));
                    st2(c1w + row * 512 + ucol, f2bf(c));
                }
            }
            flag_arrive(grp + utp, t + 1);   // publishes h1(t), c1(t)
        }
    } else {
        // ---------------- LSTM2 ----------------
        const int b2 = bid - NB1;
        const int rt2 = b2 >> 1, u2 = b2 & 1;
        const int ut4 = u2 * 2 + wvc;
        const int rowbase = rt2 * 64 + wvr * 32;
        const int ucol = ut4 * 16 + n;
        int* grp = bar + rt2 * 32;
        const float bi_ = bs2[ucol], bf_ = bs2[64 + ucol], bg_ = bs2[128 + ucol], bo_ = bs2[192 + ucol];
        const short* wbase = w2f + ut4 * 36864 + n * 32 + q * 8;
        const int r0 = rowbase + n, r1 = rowbase + 16 + n;

        // c1-part weights (kb 0..15) -> registers
        bf16x8 wr[16][4];
#pragma unroll
        for (int kb = 0; kb < 16; ++kb)
#pragma unroll
            for (int g = 0; g < 4; ++g)
                wr[kb][g] = *(const bf16x8*)(wbase + (kb * 4 + g) * 512);

        f32x4 c2f[2]; c2f[0] = Z4; c2f[1] = Z4;

        for (int t = 0; t < Tn; ++t) {
            flag_wait(grp, t + 1, t);   // c1(t) from L1; h2(t-1) from pair
            const short* c1r = c1g + (t & 1) * (Bn * Hn);
            const short* h2r = h2g + (t & 1) * (Bn * Fn);
            short* h2w = h2g + ((t + 1) & 1) * (Bn * Fn);
            f32x4 acc[2][4];
#pragma unroll
            for (int a = 0; a < 2; ++a)
#pragma unroll
                for (int g = 0; g < 4; ++g) acc[a][g] = Z4;

#pragma unroll
            for (int kb = 0; kb < 16; ++kb) {
                const int k = kb * 32 + q * 8;
                const bf16x8 a0 = ld16B(c1r + r0 * 512 + k);
                const bf16x8 a1 = ld16B(c1r + r1 * 512 + k);
#pragma unroll
                for (int g = 0; g < 4; ++g) {
                    acc[0][g] = __builtin_amdgcn_mfma_f32_16x16x32_bf16(a0, wr[kb][g], acc[0][g], 0, 0, 0);
                    acc[1][g] = __builtin_amdgcn_mfma_f32_16x16x32_bf16(a1, wr[kb][g], acc[1][g], 0, 0, 0);
                }
            }
#pragma unroll
            for (int kb = 16; kb < 18; ++kb) {
                const int k = (kb - 16) * 32 + q * 8;
                const bf16x8 a0 = ld16B(h2r + r0 * 64 + k);
                const bf16x8 a1 = ld16B(h2r + r1 * 64 + k);
#pragma unroll
                for (int g = 0; g < 4; ++g) {
                    const bf16x8 b = *(const bf16x8*)(wbase + (kb * 4 + g) * 512);
                    acc[0][g] = __builtin_amdgcn_mfma_f32_16x16x32_bf16(a0, b, acc[0][g], 0, 0, 0);
                    acc[1][g] = __builtin_amdgcn_mfma_f32_16x16x32_bf16(a1, b, acc[1][g], 0, 0, 0);
                }
            }
#pragma unroll
            for (int rt16 = 0; rt16 < 2; ++rt16) {
#pragma unroll
                for (int r = 0; r < 4; ++r) {
                    const float xi = acc[rt16][0][r] + bi_;
                    const float xf = acc[rt16][1][r] + bf_;
                    const float xg = acc[rt16][2][r] + bg_;
                    const float xo = acc[rt16][3][r] + bo_;
                    const float ii = sigm(xi), ff = sigm(xf), gg = tanh_(xg), oo = sigm(xo);
                    const float c = ff * c2f[rt16][r] + ii * gg;
                    c2f[rt16][r] = c;
                    const float h = oo * tanh_(c);
                    const int row = rowbase + rt16 * 16 + q * 4 + r;
                    out[(size_t)row * 65536 + (size_t)t * 64 + ucol] = c;  // output is c2
                    st2(h2w + row * 64 + ucol, f2bf(h));
                }
            }
            flag_arrive(grp + 16 + u2, t + 1);   // publishes h2(t) + done reading c1(t)
        }
    }
}

extern "C" void kernel_launch(void* const* d_in, const int* in_sizes, int n_in,
                              void* d_out, int out_size, void* d_ws, size_t ws_size,
                              hipStream_t stream) {
    const float* data = (const float*)d_in[0];
    const float* Wih1 = (const float*)d_in[1];
    const float* Whh1 = (const float*)d_in[2];
    const float* bih1 = (const float*)d_in[3];
    const float* bhh1 = (const float*)d_in[4];
    const float* Wih2 = (const float*)d_in[5];
    const float* Whh2 = (const float*)d_in[6];
    const float* bih2 = (const float*)d_in[7];
    const float* bhh2 = (const float*)d_in[8];
    float* out = (float*)d_out;

    char* w = (char*)d_ws;
    short* h1g = (short*)(w + 0);          // 2 * 512*512*2 = 1,048,576
    short* c1g = (short*)(w + 1048576);    // 1,048,576
    short* h2g = (short*)(w + 2097152);    // 2 * 512*64*2 = 131,072
    short* w2f = (short*)(w + 2228224);    // 256*576*2 = 294,912
    short* w1f = (short*)(w + 2523136);    // 2048*576*2 = 2,359,296
    float* bs1 = (float*)(w + 4882432);    // 8,192
    float* bs2 = (float*)(w + 4890624);    // 1,024
    unsigned* bar = (unsigned*)(w + 4891648); // 4 KB: 8 groups x 32 words (padded)

    hipLaunchKernelGGL(prep_kernel, dim3(1024), dim3(256), 0, stream,
                       Wih1, Whh1, Wih2, Whh2, bih1, bhh1, bih2, bhh2,
                       h1g, h2g, w1f, w2f, bs1, bs2, bar);

    hipLaunchKernelGGL(lstm_kernel, dim3(NBLK), dim3(256), 0, stream,
                       data, w1f, bs1, w2f, bs2, h1g, c1g, h2g, out, (int*)bar);
}